// Round 6
// baseline (195.692 us; speedup 1.0000x reference)
//
#include <hip/hip_runtime.h>
#include <hip/hip_bf16.h>

// Problem constants (match setup_inputs): B=2, Y=X=200, N=40000, C=128, H=4, P=8, D=32
#define BQ 2
#define YY 200
#define XX 200
#define NQ 40000
#define CC 128
#define MTOT 80000   // BQ*NQ
#define NCOL 224     // 128 (value) + 64 (off) + 32 (attn logits)
#define NTILES 5000  // MTOT/16

typedef __attribute__((ext_vector_type(8))) short short8;
typedef __attribute__((ext_vector_type(4))) float f32x4;

static __device__ __forceinline__ unsigned short f2bf(float f) {
    union { float f; unsigned int u; } v; v.f = f;
    unsigned int r = v.u + 0x7FFF + ((v.u >> 16) & 1);  // round-to-nearest-even
    return (unsigned short)(r >> 16);
}
static __device__ __forceinline__ unsigned short f2bf_hw(float f) {
    __hip_bfloat16 h = __float2bfloat16(f);
    unsigned short s;
    __builtin_memcpy(&s, &h, 2);
    return s;
}

// ---- prep: WcatT[224][128] bf16 = [Wv | Woff | Wattn] transposed ----
__global__ void prep_wcat(const float* __restrict__ Wv, const float* __restrict__ Woff,
                          const float* __restrict__ Wattn, unsigned short* __restrict__ WcatT) {
    int idx = blockIdx.x * 256 + threadIdx.x;       // 224*128 = 28672 = 112 blocks
    if (idx >= NCOL * CC) return;
    int c = idx >> 7, k = idx & 127;
    float w = (c < 128) ? Wv[k * 128 + c]
            : (c < 192) ? Woff[k * 64 + (c - 128)]
                        : Wattn[k * 32 + (c - 192)];
    WcatT[c * 128 + k] = f2bf(w);
}

// ---- prep: W12T[128][128] bf16 = (Wout1@Wout2)^T ; b12 = bout1@Wout2 + bout2 ----
__global__ void prep_w12(const float* __restrict__ Wout1, const float* __restrict__ Wout2,
                         const float* __restrict__ bout1, const float* __restrict__ bout2,
                         unsigned short* __restrict__ W12T, float* __restrict__ b12) {
    int idx = blockIdx.x * 256 + threadIdx.x;       // 16384 = 64 blocks
    int c = idx >> 7, k = idx & 127;
    float s = 0.f;
    for (int j = 0; j < 128; ++j) s += Wout1[k * 128 + j] * Wout2[j * 128 + c];
    W12T[c * 128 + k] = f2bf(s);
    if (k == 0) {
        float t = bout2[c];
        for (int j = 0; j < 128; ++j) t += bout1[j] * Wout2[j * 128 + c];
        b12[c] = t;
    }
}

// ---- qsum: q_bf = bf16(query + qpos), pure streaming ----
__global__ __launch_bounds__(256) void qsum_kernel(const float* __restrict__ query,
                                                   const float* __restrict__ qpos,
                                                   unsigned short* __restrict__ qbf) {
    const size_t total = (size_t)MTOT * CC / 8;   // 1,280,000 chunks of 8 floats
    for (size_t c = (size_t)blockIdx.x * 256 + threadIdx.x; c < total;
         c += (size_t)gridDim.x * 256) {
        const float4* a = (const float4*)(query + c * 8);
        const float4* b = (const float4*)(qpos + c * 8);
        float4 a0 = a[0], a1 = a[1], b0 = b[0], b1 = b[1];
        short8 w;
        w[0] = (short)f2bf_hw(a0.x + b0.x); w[1] = (short)f2bf_hw(a0.y + b0.y);
        w[2] = (short)f2bf_hw(a0.z + b0.z); w[3] = (short)f2bf_hw(a0.w + b0.w);
        w[4] = (short)f2bf_hw(a1.x + b1.x); w[5] = (short)f2bf_hw(a1.y + b1.y);
        w[6] = (short)f2bf_hw(a1.z + b1.z); w[7] = (short)f2bf_hw(a1.w + b1.w);
        *(short8*)(qbf + c * 8) = w;
    }
}

// ---- G1: projection GEMM, N-split (each block does 7 of 14 col-tiles).
// LDS 28.7KB -> 4 blocks/CU = 16 waves/CU. A = q_bf (bf16), prefetch depth 1.
// Blocks g and g+512 share A rows and map to the same XCD (blockIdx%8 equal).
__global__ __launch_bounds__(256, 4) void g1_kernel(
    const unsigned short* __restrict__ qbf, const unsigned short* __restrict__ WcatT,
    const float* __restrict__ bv, const float* __restrict__ boff, const float* __restrict__ battn,
    unsigned short* __restrict__ value_bf, float* __restrict__ off_out, float* __restrict__ logits_out)
{
    __shared__ short8 Bfrag[28 * 64];   // 28,672 B
    const int tid = threadIdx.x;
    const int half = blockIdx.x >> 9;   // grid = 1024
    const int gblk = blockIdx.x & 511;

    // conflict-free stage of this block's 7 col-tiles
    for (int j = tid; j < 28 * 64; j += 256) {
        int frag = j >> 6, within = j & 63;
        int t = frag >> 2, ks = frag & 3;
        int kq = within >> 4, ar = within & 15;
        int tg = half * 7 + t;
        int i = (tg * 16 + ar) * 16 + ks * 4 + kq;
        Bfrag[j] = *(const short8*)(WcatT + (size_t)i * 8);
    }
    __syncthreads();

    const int lane = tid & 63;
    const int arow = lane & 15, kq = lane >> 4;
    const int wid = gblk * 4 + (tid >> 6);
    const int nw = 2048;

    float bias[7];
#pragma unroll
    for (int t = 0; t < 7; ++t) {
        int tg = half * 7 + t;
        bias[t] = (tg < 8) ? bv[tg * 16 + arow]
                : (tg < 12) ? boff[(tg - 8) * 16 + arow]
                            : battn[(tg - 12) * 16 + arow];
    }

    short8 afc[4], afn[4];
    {
        const char* pa = (const char*)qbf + (size_t)(wid * 16 + arow) * 256 + kq * 16;
#pragma unroll
        for (int ks = 0; ks < 4; ++ks) afc[ks] = *(const short8*)(pa + ks * 64);
    }

    for (int tile = wid; tile < NTILES; tile += nw) {
        int nt = tile + nw;
        if (nt < NTILES) {
            const char* pa = (const char*)qbf + (size_t)(nt * 16 + arow) * 256 + kq * 16;
#pragma unroll
            for (int ks = 0; ks < 4; ++ks) afn[ks] = *(const short8*)(pa + ks * 64);
        }

        f32x4 acc[7];
#pragma unroll
        for (int t = 0; t < 7; ++t) acc[t] = (f32x4){0.f, 0.f, 0.f, 0.f};

#pragma unroll
        for (int ks = 0; ks < 4; ++ks) {
#pragma unroll
            for (int t = 0; t < 7; ++t) {
                short8 b = Bfrag[(t * 4 + ks) * 64 + lane];
                acc[t] = __builtin_amdgcn_mfma_f32_16x16x32_bf16(afc[ks], b, acc[t], 0, 0, 0);
            }
        }

#pragma unroll
        for (int t = 0; t < 7; ++t) {
            int tg = half * 7 + t;
#pragma unroll
            for (int rr = 0; rr < 4; ++rr) {
                size_t grow = (size_t)(tile * 16 + kq * 4 + rr);
                float vv = acc[t][rr] + bias[t];
                if (tg < 8)
                    value_bf[grow * 128 + tg * 16 + arow] = f2bf_hw(vv);
                else if (tg < 12)
                    off_out[grow * 64 + (tg - 8) * 16 + arow] = vv;
                else
                    logits_out[grow * 32 + (tg - 12) * 16 + arow] = vv;
            }
        }

#pragma unroll
        for (int ks = 0; ks < 4; ++ks) afc[ks] = afn[ks];
    }
}

// ---- sampling: LDS-precomputed corner addresses + validity-folded weights,
//      paired-channel gathers (u32 = 2 bf16), 2 samples per iteration per query ----
__global__ __launch_bounds__(256) void sample_kernel(
    const unsigned short* __restrict__ value_bf, const float* __restrict__ off_in,
    const float* __restrict__ logits, unsigned short* __restrict__ sampled)
{
    __shared__ int S[8][32][8];   // a00,a01,a10,a11 (byte offs), wxa,wxb,aw*wya,aw*wyb

    const int tid = threadIdx.x;
    const int qi = tid >> 5;
    const int lane = tid & 31;
    const int r = blockIdx.x * 8 + qi;          // query row, 0..79999
    const int b = (r >= NQ) ? 1 : 0;
    const int n = r - b * NQ;
    const int yq = n / XX, xq = n - yq * XX;

    // ---- phase 1: per-sample setup (lane = hp) ----
    {
        float lg = logits[(size_t)r * 32 + lane];
        float m = lg;
        m = fmaxf(m, __shfl_xor(m, 1));
        m = fmaxf(m, __shfl_xor(m, 2));
        m = fmaxf(m, __shfl_xor(m, 4));
        float e = __expf(lg - m);
        float s = e;
        s += __shfl_xor(s, 1);
        s += __shfl_xor(s, 2);
        s += __shfl_xor(s, 4);
        float aw = e / s;

        // faithful reference quirk: x-coord = yq + off0, y-coord = xq + off1
        float2 o = ((const float2*)(off_in + (size_t)r * 64))[lane];
        float gx = (float)yq + o.x;
        float gy = (float)xq + o.y;
        float fx = floorf(gx), fy = floorf(gy);
        int x0 = (int)fx, y0 = (int)fy;
        float wx1 = gx - fx, wy1 = gy - fy;
        float vx0 = ((unsigned)x0 < XX) ? 1.f : 0.f;
        float vx1 = ((unsigned)(x0 + 1) < XX) ? 1.f : 0.f;
        float vy0 = ((unsigned)y0 < YY) ? 1.f : 0.f;
        float vy1 = ((unsigned)(y0 + 1) < YY) ? 1.f : 0.f;
        int x0c = min(max(x0, 0), XX - 1);
        int x1c = min(max(x0 + 1, 0), XX - 1);
        int y0c = min(max(y0, 0), YY - 1);
        int y1c = min(max(y0 + 1, 0), YY - 1);
        int hb = (lane >> 3) * 64;                 // head byte offset within 256B row
        int rowA = y0c * XX, rowB = y1c * XX;
        int4 addrs;
        addrs.x = (rowA + x0c) * 256 + hb;
        addrs.y = (rowA + x1c) * 256 + hb;
        addrs.z = (rowB + x0c) * 256 + hb;
        addrs.w = (rowB + x1c) * 256 + hb;
        int4 wts;
        wts.x = __float_as_int((1.f - wx1) * vx0);
        wts.y = __float_as_int(wx1 * vx1);
        wts.z = __float_as_int(aw * (1.f - wy1) * vy0);
        wts.w = __float_as_int(aw * wy1 * vy1);
        *(int4*)&S[qi][lane][0] = addrs;
        *(int4*)&S[qi][lane][4] = wts;
    }
    __syncthreads();

    // ---- phase 2: gather + weighted accumulate ----
    const char* vb = (const char*)(value_bf + (size_t)b * NQ * 128);
    const int cb = (lane & 15) * 4;    // channel-pair byte offset within head
    const int g16 = lane >> 4;         // 0 -> heads 0,1 ; 1 -> heads 2,3

    float2 acc[2];
    acc[0] = make_float2(0.f, 0.f);
    acc[1] = make_float2(0.f, 0.f);

#pragma unroll
    for (int i = 0; i < 16; ++i) {
        const int hp = g16 * 16 + i;
        int4 ai = *(const int4*)&S[qi][hp][0];
        int4 wi = *(const int4*)&S[qi][hp][4];
        float wxa = __int_as_float(wi.x);
        float wxb = __int_as_float(wi.y);
        float wya = __int_as_float(wi.z);
        float wyb = __int_as_float(wi.w);

        unsigned int u00 = *(const unsigned int*)(vb + ai.x + cb);
        unsigned int u01 = *(const unsigned int*)(vb + ai.y + cb);
        unsigned int u10 = *(const unsigned int*)(vb + ai.z + cb);
        unsigned int u11 = *(const unsigned int*)(vb + ai.w + cb);

        float f00l = __uint_as_float(u00 << 16), f00h = __uint_as_float(u00 & 0xFFFF0000u);
        float f01l = __uint_as_float(u01 << 16), f01h = __uint_as_float(u01 & 0xFFFF0000u);
        float f10l = __uint_as_float(u10 << 16), f10h = __uint_as_float(u10 & 0xFFFF0000u);
        float f11l = __uint_as_float(u11 << 16), f11h = __uint_as_float(u11 & 0xFFFF0000u);

        float tal = fmaf(wxa, f00l, wxb * f01l);
        float tbl = fmaf(wxa, f10l, wxb * f11l);
        float tah = fmaf(wxa, f00h, wxb * f01h);
        float tbh = fmaf(wxa, f10h, wxb * f11h);

        const int j = i >> 3;   // compile-time after unroll
        acc[j].x = fmaf(wya, tal, acc[j].x);
        acc[j].x = fmaf(wyb, tbl, acc[j].x);
        acc[j].y = fmaf(wya, tah, acc[j].y);
        acc[j].y = fmaf(wyb, tbh, acc[j].y);
    }

    // write: acc[j] -> head h = g16*2 + j, channel pair (lane&15)*2, packed u32
    char* sp = (char*)(sampled + (size_t)r * 128);
#pragma unroll
    for (int j = 0; j < 2; ++j) {
        unsigned int packed = ((unsigned int)f2bf(acc[j].y) << 16) | (unsigned int)f2bf(acc[j].x);
        *(unsigned int*)(sp + (g16 * 2 + j) * 64 + cb) = packed;
    }
}

// ---- G2: out = sampled @ W12 + b12 + query (residual). B in LDS fragment order,
// 4 blocks/CU, prefetch depth 1. ----
__global__ __launch_bounds__(256, 4) void g2_kernel(
    const unsigned short* __restrict__ sampled, const unsigned short* __restrict__ W12T,
    const float* __restrict__ b12, const float* __restrict__ query, float* __restrict__ out)
{
    __shared__ short8 Bfrag[32 * 64];   // 32,768 B
    const int tid = threadIdx.x;

    for (int j = tid; j < 32 * 64; j += 256) {
        int frag = j >> 6, within = j & 63;
        int t = frag >> 2, ks = frag & 3;
        int kq = within >> 4, ar = within & 15;
        int i = (t * 16 + ar) * 16 + ks * 4 + kq;
        Bfrag[j] = *(const short8*)(W12T + (size_t)i * 8);
    }
    __syncthreads();

    const int lane = tid & 63;
    const int arow = lane & 15, kq = lane >> 4;
    const int wid = blockIdx.x * 4 + (tid >> 6);
    const int nw = gridDim.x * 4;

    float bias[8];
#pragma unroll
    for (int t = 0; t < 8; ++t) bias[t] = b12[t * 16 + arow];

    short8 afc[4], afn[4];
    {
        const char* pa = (const char*)sampled + (size_t)(wid * 16 + arow) * 256 + kq * 16;
#pragma unroll
        for (int ks = 0; ks < 4; ++ks) afc[ks] = *(const short8*)(pa + ks * 64);
    }

    for (int tile = wid; tile < NTILES; tile += nw) {
        int nt = tile + nw;
        if (nt < NTILES) {
            const char* pa = (const char*)sampled + (size_t)(nt * 16 + arow) * 256 + kq * 16;
#pragma unroll
            for (int ks = 0; ks < 4; ++ks) afn[ks] = *(const short8*)(pa + ks * 64);
        }

        f32x4 acc[8];
#pragma unroll
        for (int t = 0; t < 8; ++t) acc[t] = (f32x4){0.f, 0.f, 0.f, 0.f};

#pragma unroll
        for (int ks = 0; ks < 4; ++ks) {
#pragma unroll
            for (int t = 0; t < 8; ++t) {
                short8 b = Bfrag[(t * 4 + ks) * 64 + lane];
                acc[t] = __builtin_amdgcn_mfma_f32_16x16x32_bf16(afc[ks], b, acc[t], 0, 0, 0);
            }
        }

#pragma unroll
        for (int t = 0; t < 8; ++t) {
#pragma unroll
            for (int rr = 0; rr < 4; ++rr) {
                size_t grow = (size_t)(tile * 16 + kq * 4 + rr);
                size_t idx = grow * 128 + t * 16 + arow;
                out[idx] = acc[t][rr] + bias[t] + query[idx];
            }
        }

#pragma unroll
        for (int ks = 0; ks < 4; ++ks) afc[ks] = afn[ks];
    }
}

extern "C" void kernel_launch(void* const* d_in, const int* in_sizes, int n_in,
                              void* d_out, int out_size, void* d_ws, size_t ws_size,
                              hipStream_t stream) {
    const float* query = (const float*)d_in[0];
    const float* qpos  = (const float*)d_in[1];
    const float* Wv    = (const float*)d_in[2];
    const float* bv    = (const float*)d_in[3];
    const float* Woff  = (const float*)d_in[4];
    const float* boff  = (const float*)d_in[5];
    const float* Wattn = (const float*)d_in[6];
    const float* battn = (const float*)d_in[7];
    const float* Wout1 = (const float*)d_in[8];
    const float* bout1 = (const float*)d_in[9];
    const float* Wout2 = (const float*)d_in[10];
    const float* bout2 = (const float*)d_in[11];
    float* out = (float*)d_out;

    char* ws = (char*)d_ws;
    unsigned short* value_bf = (unsigned short*)(ws);                 // 80000*128*2 = 20,480,000
    float*          off_buf  = (float*)(ws + 20480000);               // 80000*64*4  = 20,480,000
    float*          logits   = (float*)(ws + 40960000);               // 80000*32*4  = 10,240,000
    unsigned short* sampled  = (unsigned short*)(ws + 51200000);      // 80000*128*2 = 20,480,000
    unsigned short* WcatT    = (unsigned short*)(ws + 71680000);      // 224*128*2   = 57,344
    unsigned short* W12T     = (unsigned short*)(ws + 71680000 + 57344);  // 128*128*2 = 32,768
    float*          b12      = (float*)(ws + 71680000 + 57344 + 32768);   // 512

    // qbf aliases `sampled`: qbf is dead before sample_kernel writes sampled.
    unsigned short* qbf = sampled;

    prep_wcat<<<112, 256, 0, stream>>>(Wv, Woff, Wattn, WcatT);
    prep_w12<<<64, 256, 0, stream>>>(Wout1, Wout2, bout1, bout2, W12T, b12);
    qsum_kernel<<<2048, 256, 0, stream>>>(query, qpos, qbf);
    g1_kernel<<<1024, 256, 0, stream>>>(qbf, WcatT, bv, boff, battn,
                                        value_bf, off_buf, logits);
    sample_kernel<<<MTOT / 8, 256, 0, stream>>>(value_bf, off_buf, logits, sampled);
    g2_kernel<<<1024, 256, 0, stream>>>(sampled, W12T, b12, query, out);
}

// Round 7
// 126.241 us; speedup vs baseline: 1.5501x; 1.5501x over previous
//
#include <hip/hip_runtime.h>
#include <hip/hip_bf16.h>

// Problem constants (match setup_inputs): B=2, Y=X=200, N=40000, C=128, H=4, P=8, D=32
#define BQ 2
#define YY 200
#define XX 200
#define NQ 40000
#define CC 128
#define MTOT 80000   // BQ*NQ
#define NCOL 224     // 128 (value) + 64 (off) + 32 (attn logits)
#define NTILES 5000  // MTOT/16

typedef __attribute__((ext_vector_type(8))) short short8;
typedef __attribute__((ext_vector_type(4))) short short4v;
typedef __attribute__((ext_vector_type(4))) float f32x4;

static __device__ __forceinline__ unsigned short f2bf(float f) {
    union { float f; unsigned int u; } v; v.f = f;
    unsigned int r = v.u + 0x7FFF + ((v.u >> 16) & 1);  // round-to-nearest-even
    return (unsigned short)(r >> 16);
}
static __device__ __forceinline__ unsigned short f2bf_hw(float f) {
    __hip_bfloat16 h = __float2bfloat16(f);
    unsigned short s;
    __builtin_memcpy(&s, &h, 2);
    return s;
}

// ---- prep: WcatT[224][128] bf16 = [Wv | Woff | Wattn] transposed ----
__global__ void prep_wcat(const float* __restrict__ Wv, const float* __restrict__ Woff,
                          const float* __restrict__ Wattn, unsigned short* __restrict__ WcatT) {
    int idx = blockIdx.x * 256 + threadIdx.x;       // 224*128 = 28672 = 112 blocks
    if (idx >= NCOL * CC) return;
    int c = idx >> 7, k = idx & 127;
    float w = (c < 128) ? Wv[k * 128 + c]
            : (c < 192) ? Woff[k * 64 + (c - 128)]
                        : Wattn[k * 32 + (c - 192)];
    WcatT[c * 128 + k] = f2bf(w);
}

// ---- prep: W12T[128][128] bf16 = (Wout1@Wout2)^T ; b12 = bout1@Wout2 + bout2 ----
__global__ void prep_w12(const float* __restrict__ Wout1, const float* __restrict__ Wout2,
                         const float* __restrict__ bout1, const float* __restrict__ bout2,
                         unsigned short* __restrict__ W12T, float* __restrict__ b12) {
    int idx = blockIdx.x * 256 + threadIdx.x;       // 16384 = 64 blocks
    int c = idx >> 7, k = idx & 127;
    float s = 0.f;
    for (int j = 0; j < 128; ++j) s += Wout1[k * 128 + j] * Wout2[j * 128 + c];
    W12T[c * 128 + k] = f2bf(s);
    if (k == 0) {
        float t = bout2[c];
        for (int j = 0; j < 128; ++j) t += bout1[j] * Wout2[j * 128 + c];
        b12[c] = t;
    }
}

// ---- qsum: q_bf = bf16(query + qpos), pure streaming ----
__global__ __launch_bounds__(256) void qsum_kernel(const float* __restrict__ query,
                                                   const float* __restrict__ qpos,
                                                   unsigned short* __restrict__ qbf) {
    const size_t total = (size_t)MTOT * CC / 8;   // 1,280,000 chunks of 8 floats
    for (size_t c = (size_t)blockIdx.x * 256 + threadIdx.x; c < total;
         c += (size_t)gridDim.x * 256) {
        const float4* a = (const float4*)(query + c * 8);
        const float4* b = (const float4*)(qpos + c * 8);
        float4 a0 = a[0], a1 = a[1], b0 = b[0], b1 = b[1];
        short8 w;
        w[0] = (short)f2bf_hw(a0.x + b0.x); w[1] = (short)f2bf_hw(a0.y + b0.y);
        w[2] = (short)f2bf_hw(a0.z + b0.z); w[3] = (short)f2bf_hw(a0.w + b0.w);
        w[4] = (short)f2bf_hw(a1.x + b1.x); w[5] = (short)f2bf_hw(a1.y + b1.y);
        w[6] = (short)f2bf_hw(a1.z + b1.z); w[7] = (short)f2bf_hw(a1.w + b1.w);
        *(short8*)(qbf + c * 8) = w;
    }
}

// ---- G1: projection GEMM, B fully in REGISTERS (no LDS, no barrier).
// 4 groups by blockIdx&3: {value t0-3, value t4-7, off t8-11, logits t12-13}.
// Swapped-operand MFMA => D fragment holds 4 consecutive output cols per lane:
// value: one 8B packed-bf16 store per tile; off/logits: one float4 store.
// Bias folded into acc init. ~116 VGPR -> 16 waves/CU.
__global__ __launch_bounds__(256, 2) void g1_kernel(
    const unsigned short* __restrict__ qbf, const unsigned short* __restrict__ WcatT,
    const float* __restrict__ bv, const float* __restrict__ boff, const float* __restrict__ battn,
    unsigned short* __restrict__ value_bf, float* __restrict__ off_out, float* __restrict__ logits_out)
{
    const int tid = threadIdx.x;
    const int group = blockIdx.x & 3;
    const int gblk = blockIdx.x >> 2;          // 0..255
    const int lane = tid & 63;
    const int arow = lane & 15, kq = lane >> 4;
    const int wid = gblk * 4 + (tid >> 6);     // 0..1023 within group
    const int tg0 = group * 4;
    const int NT = (group == 3) ? 2 : 4;

    // B fragments in registers: bf[t][ks] = WcatT[(tg0+t)*16+arow][ks*32+kq*8 ..]
    short8 bf[4][4];
#pragma unroll
    for (int t = 0; t < 4; ++t) {
        if (t < NT) {
#pragma unroll
            for (int ks = 0; ks < 4; ++ks)
                bf[t][ks] = *(const short8*)(WcatT + (size_t)((tg0 + t) * 16 + arow) * 128 + ks * 32 + kq * 8);
        }
    }

    // bias vectors: 4 consecutive output cols per lane (col base = (tg0+t)*16 + kq*4)
    f32x4 biasv[4];
#pragma unroll
    for (int t = 0; t < 4; ++t) {
        if (t < NT) {
            const float* bp = (group < 2) ? (bv + (tg0 + t) * 16 + kq * 4)
                            : (group == 2) ? (boff + (tg0 + t - 8) * 16 + kq * 4)
                                           : (battn + (tg0 + t - 12) * 16 + kq * 4);
            float4 b4 = *(const float4*)bp;
            biasv[t] = (f32x4){b4.x, b4.y, b4.z, b4.w};
        }
    }

    for (int tile = wid; tile < NTILES; tile += 1024) {
        const char* pa = (const char*)qbf + (size_t)(tile * 16 + arow) * 256 + kq * 16;
        short8 af[4];
#pragma unroll
        for (int ks = 0; ks < 4; ++ks) af[ks] = *(const short8*)(pa + ks * 64);

        f32x4 acc[4];
#pragma unroll
        for (int t = 0; t < 4; ++t) acc[t] = biasv[t];

#pragma unroll
        for (int ks = 0; ks < 4; ++ks) {
#pragma unroll
            for (int t = 0; t < 4; ++t) {
                if (t < NT)   // swapped operands -> transposed fragment
                    acc[t] = __builtin_amdgcn_mfma_f32_16x16x32_bf16(bf[t][ks], af[ks], acc[t], 0, 0, 0);
            }
        }

        const int row = tile * 16 + arow;
        if (group < 2) {
#pragma unroll
            for (int t = 0; t < 4; ++t) {
                short4v pv;
                pv[0] = (short)f2bf_hw(acc[t][0]); pv[1] = (short)f2bf_hw(acc[t][1]);
                pv[2] = (short)f2bf_hw(acc[t][2]); pv[3] = (short)f2bf_hw(acc[t][3]);
                *(short4v*)(value_bf + (size_t)row * 128 + (tg0 + t) * 16 + kq * 4) = pv;
            }
        } else if (group == 2) {
#pragma unroll
            for (int t = 0; t < 4; ++t) {
                float4 o = make_float4(acc[t][0], acc[t][1], acc[t][2], acc[t][3]);
                *(float4*)(off_out + (size_t)row * 64 + (tg0 + t - 8) * 16 + kq * 4) = o;
            }
        } else {
#pragma unroll
            for (int t = 0; t < 2; ++t) {
                float4 o = make_float4(acc[t][0], acc[t][1], acc[t][2], acc[t][3]);
                *(float4*)(logits_out + (size_t)row * 32 + (tg0 + t - 12) * 16 + kq * 4) = o;
            }
        }
    }
}

// ---- sampling: LDS-precomputed corner addresses + validity-folded weights,
//      paired-channel gathers (u32 = 2 bf16), 2 samples per iteration per query ----
__global__ __launch_bounds__(256) void sample_kernel(
    const unsigned short* __restrict__ value_bf, const float* __restrict__ off_in,
    const float* __restrict__ logits, unsigned short* __restrict__ sampled)
{
    __shared__ int S[8][32][8];   // a00,a01,a10,a11 (byte offs), wxa,wxb,aw*wya,aw*wyb

    const int tid = threadIdx.x;
    const int qi = tid >> 5;
    const int lane = tid & 31;
    const int r = blockIdx.x * 8 + qi;          // query row, 0..79999
    const int b = (r >= NQ) ? 1 : 0;
    const int n = r - b * NQ;
    const int yq = n / XX, xq = n - yq * XX;

    // ---- phase 1: per-sample setup (lane = hp) ----
    {
        float lg = logits[(size_t)r * 32 + lane];
        float m = lg;
        m = fmaxf(m, __shfl_xor(m, 1));
        m = fmaxf(m, __shfl_xor(m, 2));
        m = fmaxf(m, __shfl_xor(m, 4));
        float e = __expf(lg - m);
        float s = e;
        s += __shfl_xor(s, 1);
        s += __shfl_xor(s, 2);
        s += __shfl_xor(s, 4);
        float aw = e / s;

        // faithful reference quirk: x-coord = yq + off0, y-coord = xq + off1
        float2 o = ((const float2*)(off_in + (size_t)r * 64))[lane];
        float gx = (float)yq + o.x;
        float gy = (float)xq + o.y;
        float fx = floorf(gx), fy = floorf(gy);
        int x0 = (int)fx, y0 = (int)fy;
        float wx1 = gx - fx, wy1 = gy - fy;
        float vx0 = ((unsigned)x0 < XX) ? 1.f : 0.f;
        float vx1 = ((unsigned)(x0 + 1) < XX) ? 1.f : 0.f;
        float vy0 = ((unsigned)y0 < YY) ? 1.f : 0.f;
        float vy1 = ((unsigned)(y0 + 1) < YY) ? 1.f : 0.f;
        int x0c = min(max(x0, 0), XX - 1);
        int x1c = min(max(x0 + 1, 0), XX - 1);
        int y0c = min(max(y0, 0), YY - 1);
        int y1c = min(max(y0 + 1, 0), YY - 1);
        int hb = (lane >> 3) * 64;                 // head byte offset within 256B row
        int rowA = y0c * XX, rowB = y1c * XX;
        int4 addrs;
        addrs.x = (rowA + x0c) * 256 + hb;
        addrs.y = (rowA + x1c) * 256 + hb;
        addrs.z = (rowB + x0c) * 256 + hb;
        addrs.w = (rowB + x1c) * 256 + hb;
        int4 wts;
        wts.x = __float_as_int((1.f - wx1) * vx0);
        wts.y = __float_as_int(wx1 * vx1);
        wts.z = __float_as_int(aw * (1.f - wy1) * vy0);
        wts.w = __float_as_int(aw * wy1 * vy1);
        *(int4*)&S[qi][lane][0] = addrs;
        *(int4*)&S[qi][lane][4] = wts;
    }
    __syncthreads();

    // ---- phase 2: gather + weighted accumulate ----
    const char* vb = (const char*)(value_bf + (size_t)b * NQ * 128);
    const int cb = (lane & 15) * 4;    // channel-pair byte offset within head
    const int g16 = lane >> 4;         // 0 -> heads 0,1 ; 1 -> heads 2,3

    float2 acc[2];
    acc[0] = make_float2(0.f, 0.f);
    acc[1] = make_float2(0.f, 0.f);

#pragma unroll
    for (int i = 0; i < 16; ++i) {
        const int hp = g16 * 16 + i;
        int4 ai = *(const int4*)&S[qi][hp][0];
        int4 wi = *(const int4*)&S[qi][hp][4];
        float wxa = __int_as_float(wi.x);
        float wxb = __int_as_float(wi.y);
        float wya = __int_as_float(wi.z);
        float wyb = __int_as_float(wi.w);

        unsigned int u00 = *(const unsigned int*)(vb + ai.x + cb);
        unsigned int u01 = *(const unsigned int*)(vb + ai.y + cb);
        unsigned int u10 = *(const unsigned int*)(vb + ai.z + cb);
        unsigned int u11 = *(const unsigned int*)(vb + ai.w + cb);

        float f00l = __uint_as_float(u00 << 16), f00h = __uint_as_float(u00 & 0xFFFF0000u);
        float f01l = __uint_as_float(u01 << 16), f01h = __uint_as_float(u01 & 0xFFFF0000u);
        float f10l = __uint_as_float(u10 << 16), f10h = __uint_as_float(u10 & 0xFFFF0000u);
        float f11l = __uint_as_float(u11 << 16), f11h = __uint_as_float(u11 & 0xFFFF0000u);

        float tal = fmaf(wxa, f00l, wxb * f01l);
        float tbl = fmaf(wxa, f10l, wxb * f11l);
        float tah = fmaf(wxa, f00h, wxb * f01h);
        float tbh = fmaf(wxa, f10h, wxb * f11h);

        const int j = i >> 3;   // compile-time after unroll
        acc[j].x = fmaf(wya, tal, acc[j].x);
        acc[j].x = fmaf(wyb, tbl, acc[j].x);
        acc[j].y = fmaf(wya, tah, acc[j].y);
        acc[j].y = fmaf(wyb, tbh, acc[j].y);
    }

    // write: acc[j] -> head h = g16*2 + j, channel pair (lane&15)*2, packed u32
    char* sp = (char*)(sampled + (size_t)r * 128);
#pragma unroll
    for (int j = 0; j < 2; ++j) {
        unsigned int packed = ((unsigned int)f2bf(acc[j].y) << 16) | (unsigned int)f2bf(acc[j].x);
        *(unsigned int*)(sp + (g16 * 2 + j) * 64 + cb) = packed;
    }
}

// ---- G2: out = sampled @ W12 + b12 + query. B in registers, 2 groups of 4 tiles,
// swapped MFMA -> float4 stores with fused float4 residual read. ----
__global__ __launch_bounds__(256, 2) void g2_kernel(
    const unsigned short* __restrict__ sampled, const unsigned short* __restrict__ W12T,
    const float* __restrict__ b12, const float* __restrict__ query, float* __restrict__ out)
{
    const int tid = threadIdx.x;
    const int group = blockIdx.x & 1;
    const int gblk = blockIdx.x >> 1;          // 0..511
    const int lane = tid & 63;
    const int arow = lane & 15, kq = lane >> 4;
    const int wid = gblk * 4 + (tid >> 6);     // 0..2047 within group
    const int tg0 = group * 4;

    short8 bf[4][4];
#pragma unroll
    for (int t = 0; t < 4; ++t)
#pragma unroll
        for (int ks = 0; ks < 4; ++ks)
            bf[t][ks] = *(const short8*)(W12T + (size_t)((tg0 + t) * 16 + arow) * 128 + ks * 32 + kq * 8);

    f32x4 biasv[4];
#pragma unroll
    for (int t = 0; t < 4; ++t) {
        float4 b4 = *(const float4*)(b12 + (tg0 + t) * 16 + kq * 4);
        biasv[t] = (f32x4){b4.x, b4.y, b4.z, b4.w};
    }

    for (int tile = wid; tile < NTILES; tile += 2048) {
        const char* pa = (const char*)sampled + (size_t)(tile * 16 + arow) * 256 + kq * 16;
        short8 af[4];
#pragma unroll
        for (int ks = 0; ks < 4; ++ks) af[ks] = *(const short8*)(pa + ks * 64);

        f32x4 acc[4];
#pragma unroll
        for (int t = 0; t < 4; ++t) acc[t] = biasv[t];

#pragma unroll
        for (int ks = 0; ks < 4; ++ks)
#pragma unroll
            for (int t = 0; t < 4; ++t)
                acc[t] = __builtin_amdgcn_mfma_f32_16x16x32_bf16(bf[t][ks], af[ks], acc[t], 0, 0, 0);

        const int row = tile * 16 + arow;
#pragma unroll
        for (int t = 0; t < 4; ++t) {
            size_t idx = (size_t)row * 128 + (tg0 + t) * 16 + kq * 4;
            float4 q4 = *(const float4*)(query + idx);
            float4 o = make_float4(acc[t][0] + q4.x, acc[t][1] + q4.y,
                                   acc[t][2] + q4.z, acc[t][3] + q4.w);
            *(float4*)(out + idx) = o;
        }
    }
}

extern "C" void kernel_launch(void* const* d_in, const int* in_sizes, int n_in,
                              void* d_out, int out_size, void* d_ws, size_t ws_size,
                              hipStream_t stream) {
    const float* query = (const float*)d_in[0];
    const float* qpos  = (const float*)d_in[1];
    const float* Wv    = (const float*)d_in[2];
    const float* bv    = (const float*)d_in[3];
    const float* Woff  = (const float*)d_in[4];
    const float* boff  = (const float*)d_in[5];
    const float* Wattn = (const float*)d_in[6];
    const float* battn = (const float*)d_in[7];
    const float* Wout1 = (const float*)d_in[8];
    const float* bout1 = (const float*)d_in[9];
    const float* Wout2 = (const float*)d_in[10];
    const float* bout2 = (const float*)d_in[11];
    float* out = (float*)d_out;

    char* ws = (char*)d_ws;
    unsigned short* value_bf = (unsigned short*)(ws);                 // 80000*128*2 = 20,480,000
    float*          off_buf  = (float*)(ws + 20480000);               // 80000*64*4  = 20,480,000
    float*          logits   = (float*)(ws + 40960000);               // 80000*32*4  = 10,240,000
    unsigned short* sampled  = (unsigned short*)(ws + 51200000);      // 80000*128*2 = 20,480,000
    unsigned short* WcatT    = (unsigned short*)(ws + 71680000);      // 224*128*2   = 57,344
    unsigned short* W12T     = (unsigned short*)(ws + 71680000 + 57344);  // 128*128*2 = 32,768
    float*          b12      = (float*)(ws + 71680000 + 57344 + 32768);   // 512

    // qbf aliases `sampled`: qbf is dead before sample_kernel writes sampled.
    unsigned short* qbf = sampled;

    prep_wcat<<<112, 256, 0, stream>>>(Wv, Woff, Wattn, WcatT);
    prep_w12<<<64, 256, 0, stream>>>(Wout1, Wout2, bout1, bout2, W12T, b12);
    qsum_kernel<<<2048, 256, 0, stream>>>(query, qpos, qbf);
    g1_kernel<<<1024, 256, 0, stream>>>(qbf, WcatT, bv, boff, battn,
                                        value_bf, off_buf, logits);
    sample_kernel<<<MTOT / 8, 256, 0, stream>>>(value_bf, off_buf, logits, sampled);
    g2_kernel<<<1024, 256, 0, stream>>>(sampled, W12T, b12, query, out);
}

// Round 8
// 120.960 us; speedup vs baseline: 1.6178x; 1.0437x over previous
//
#include <hip/hip_runtime.h>
#include <hip/hip_bf16.h>

// Problem constants (match setup_inputs): B=2, Y=X=200, N=40000, C=128, H=4, P=8, D=32
#define BQ 2
#define YY 200
#define XX 200
#define NQ 40000
#define CC 128
#define MTOT 80000   // BQ*NQ
#define NCOL 224     // 128 (value) + 64 (off) + 32 (attn logits)
#define NTILES 5000  // MTOT/16

typedef __attribute__((ext_vector_type(8))) short short8;
typedef __attribute__((ext_vector_type(4))) short short4v;
typedef __attribute__((ext_vector_type(4))) float f32x4;
typedef __attribute__((ext_vector_type(2))) float f32x2;

static __device__ __forceinline__ unsigned short f2bf(float f) {
    union { float f; unsigned int u; } v; v.f = f;
    unsigned int r = v.u + 0x7FFF + ((v.u >> 16) & 1);  // round-to-nearest-even
    return (unsigned short)(r >> 16);
}
static __device__ __forceinline__ unsigned short f2bf_hw(float f) {
    __hip_bfloat16 h = __float2bfloat16(f);
    unsigned short s;
    __builtin_memcpy(&s, &h, 2);
    return s;
}

// ---- prep: WcatT[224][128] bf16 = [Wv | Woff | Wattn] transposed ----
__global__ void prep_wcat(const float* __restrict__ Wv, const float* __restrict__ Woff,
                          const float* __restrict__ Wattn, unsigned short* __restrict__ WcatT) {
    int idx = blockIdx.x * 256 + threadIdx.x;       // 224*128 = 28672 = 112 blocks
    if (idx >= NCOL * CC) return;
    int c = idx >> 7, k = idx & 127;
    float w = (c < 128) ? Wv[k * 128 + c]
            : (c < 192) ? Woff[k * 64 + (c - 128)]
                        : Wattn[k * 32 + (c - 192)];
    WcatT[c * 128 + k] = f2bf(w);
}

// ---- prep: W12T[128][128] bf16 = (Wout1@Wout2)^T ; b12 = bout1@Wout2 + bout2 ----
__global__ void prep_w12(const float* __restrict__ Wout1, const float* __restrict__ Wout2,
                         const float* __restrict__ bout1, const float* __restrict__ bout2,
                         unsigned short* __restrict__ W12T, float* __restrict__ b12) {
    int idx = blockIdx.x * 256 + threadIdx.x;       // 16384 = 64 blocks
    int c = idx >> 7, k = idx & 127;
    float s = 0.f;
    for (int j = 0; j < 128; ++j) s += Wout1[k * 128 + j] * Wout2[j * 128 + c];
    W12T[c * 128 + k] = f2bf(s);
    if (k == 0) {
        float t = bout2[c];
        for (int j = 0; j < 128; ++j) t += bout1[j] * Wout2[j * 128 + c];
        b12[c] = t;
    }
}

// ---- qsum: q_bf = bf16(query + qpos), pure streaming ----
__global__ __launch_bounds__(256) void qsum_kernel(const float* __restrict__ query,
                                                   const float* __restrict__ qpos,
                                                   unsigned short* __restrict__ qbf) {
    const size_t total = (size_t)MTOT * CC / 8;   // 1,280,000 chunks of 8 floats
    for (size_t c = (size_t)blockIdx.x * 256 + threadIdx.x; c < total;
         c += (size_t)gridDim.x * 256) {
        const float4* a = (const float4*)(query + c * 8);
        const float4* b = (const float4*)(qpos + c * 8);
        float4 a0 = a[0], a1 = a[1], b0 = b[0], b1 = b[1];
        short8 w;
        w[0] = (short)f2bf_hw(a0.x + b0.x); w[1] = (short)f2bf_hw(a0.y + b0.y);
        w[2] = (short)f2bf_hw(a0.z + b0.z); w[3] = (short)f2bf_hw(a0.w + b0.w);
        w[4] = (short)f2bf_hw(a1.x + b1.x); w[5] = (short)f2bf_hw(a1.y + b1.y);
        w[6] = (short)f2bf_hw(a1.z + b1.z); w[7] = (short)f2bf_hw(a1.w + b1.w);
        *(short8*)(qbf + c * 8) = w;
    }
}

// ---- G1: projection GEMM, B fully in REGISTERS (no LDS, no barrier).
// 4 groups by blockIdx>>8 (siblings sharing A-tiles are == mod 8 -> same XCD L2).
// Swapped-operand MFMA => D fragment holds 4 consecutive output cols per lane.
__global__ __launch_bounds__(256, 2) void g1_kernel(
    const unsigned short* __restrict__ qbf, const unsigned short* __restrict__ WcatT,
    const float* __restrict__ bv, const float* __restrict__ boff, const float* __restrict__ battn,
    unsigned short* __restrict__ value_bf, float* __restrict__ off_out, float* __restrict__ logits_out)
{
    const int tid = threadIdx.x;
    const int group = blockIdx.x >> 8;         // 0..3, siblings same XCD
    const int gblk = blockIdx.x & 255;
    const int lane = tid & 63;
    const int arow = lane & 15, kq = lane >> 4;
    const int wid = gblk * 4 + (tid >> 6);     // 0..1023 within group
    const int tg0 = group * 4;
    const int NT = (group == 3) ? 2 : 4;

    // B fragments in registers: bf[t][ks] = WcatT[(tg0+t)*16+arow][ks*32+kq*8 ..]
    short8 bf[4][4];
#pragma unroll
    for (int t = 0; t < 4; ++t) {
        if (t < NT) {
#pragma unroll
            for (int ks = 0; ks < 4; ++ks)
                bf[t][ks] = *(const short8*)(WcatT + (size_t)((tg0 + t) * 16 + arow) * 128 + ks * 32 + kq * 8);
        }
    }

    // bias vectors: 4 consecutive output cols per lane (col base = (tg0+t)*16 + kq*4)
    f32x4 biasv[4];
#pragma unroll
    for (int t = 0; t < 4; ++t) {
        if (t < NT) {
            const float* bp = (group < 2) ? (bv + (tg0 + t) * 16 + kq * 4)
                            : (group == 2) ? (boff + (tg0 + t - 8) * 16 + kq * 4)
                                           : (battn + (tg0 + t - 12) * 16 + kq * 4);
            float4 b4 = *(const float4*)bp;
            biasv[t] = (f32x4){b4.x, b4.y, b4.z, b4.w};
        }
    }

    for (int tile = wid; tile < NTILES; tile += 1024) {
        const char* pa = (const char*)qbf + (size_t)(tile * 16 + arow) * 256 + kq * 16;
        short8 af[4];
#pragma unroll
        for (int ks = 0; ks < 4; ++ks) af[ks] = *(const short8*)(pa + ks * 64);

        f32x4 acc[4];
#pragma unroll
        for (int t = 0; t < 4; ++t) acc[t] = biasv[t];

#pragma unroll
        for (int ks = 0; ks < 4; ++ks) {
#pragma unroll
            for (int t = 0; t < 4; ++t) {
                if (t < NT)   // swapped operands -> transposed fragment
                    acc[t] = __builtin_amdgcn_mfma_f32_16x16x32_bf16(bf[t][ks], af[ks], acc[t], 0, 0, 0);
            }
        }

        const int row = tile * 16 + arow;
        if (group < 2) {
#pragma unroll
            for (int t = 0; t < 4; ++t) {
                short4v pv;
                pv[0] = (short)f2bf_hw(acc[t][0]); pv[1] = (short)f2bf_hw(acc[t][1]);
                pv[2] = (short)f2bf_hw(acc[t][2]); pv[3] = (short)f2bf_hw(acc[t][3]);
                *(short4v*)(value_bf + (size_t)row * 128 + (tg0 + t) * 16 + kq * 4) = pv;
            }
        } else if (group == 2) {
#pragma unroll
            for (int t = 0; t < 4; ++t) {
                float4 o = make_float4(acc[t][0], acc[t][1], acc[t][2], acc[t][3]);
                *(float4*)(off_out + (size_t)row * 64 + (tg0 + t - 8) * 16 + kq * 4) = o;
            }
        } else {
#pragma unroll
            for (int t = 0; t < 2; ++t) {
                float4 o = make_float4(acc[t][0], acc[t][1], acc[t][2], acc[t][3]);
                *(float4*)(logits_out + (size_t)row * 32 + (tg0 + t - 12) * 16 + kq * 4) = o;
            }
        }
    }
}

// ---- sampling: bank-conflict-free S layout + packed-f32 interpolation ----
// 8 queries/block, 32 lanes per query. Phase 1: lane = (h,p) sample; store addrs
// and validity-folded weights at slot (hp&15)*2 + (hp>>4) (perm -> the two
// 16-lane halves read adjacent slots = different bank quads). Phase 2: lane owns
// a channel pair per head; lo/hi channels as float2 -> v_pk_fma_f32.
__global__ __launch_bounds__(256) void sample_kernel(
    const unsigned short* __restrict__ value_bf, const float* __restrict__ off_in,
    const float* __restrict__ logits, unsigned short* __restrict__ sampled)
{
    __shared__ int4 SA[8][33];   // corner byte-addresses (padded row: +4 banks/qi)
    __shared__ int4 SW[8][33];   // wxa, wxb, aw*wya, aw*wyb

    const int tid = threadIdx.x;
    const int qi = tid >> 5;
    const int lane = tid & 31;
    const int r = blockIdx.x * 8 + qi;          // query row, 0..79999
    const int b = (r >= NQ) ? 1 : 0;
    const int n = r - b * NQ;
    const int yq = n / XX, xq = n - yq * XX;

    // ---- phase 1: per-sample setup (lane = hp) ----
    {
        float lg = logits[(size_t)r * 32 + lane];
        float m = lg;
        m = fmaxf(m, __shfl_xor(m, 1));
        m = fmaxf(m, __shfl_xor(m, 2));
        m = fmaxf(m, __shfl_xor(m, 4));
        float e = __expf(lg - m);
        float s = e;
        s += __shfl_xor(s, 1);
        s += __shfl_xor(s, 2);
        s += __shfl_xor(s, 4);
        float aw = e / s;

        // faithful reference quirk: x-coord = yq + off0, y-coord = xq + off1
        float2 o = ((const float2*)(off_in + (size_t)r * 64))[lane];
        float gx = (float)yq + o.x;
        float gy = (float)xq + o.y;
        float fx = floorf(gx), fy = floorf(gy);
        int x0 = (int)fx, y0 = (int)fy;
        float wx1 = gx - fx, wy1 = gy - fy;
        float vx0 = ((unsigned)x0 < XX) ? 1.f : 0.f;
        float vx1 = ((unsigned)(x0 + 1) < XX) ? 1.f : 0.f;
        float vy0 = ((unsigned)y0 < YY) ? 1.f : 0.f;
        float vy1 = ((unsigned)(y0 + 1) < YY) ? 1.f : 0.f;
        int x0c = min(max(x0, 0), XX - 1);
        int x1c = min(max(x0 + 1, 0), XX - 1);
        int y0c = min(max(y0, 0), YY - 1);
        int y1c = min(max(y0 + 1, 0), YY - 1);
        int hb = (lane >> 3) * 64;                 // head byte offset within 256B row
        int rowA = y0c * XX, rowB = y1c * XX;
        int4 addrs;
        addrs.x = (rowA + x0c) * 256 + hb;
        addrs.y = (rowA + x1c) * 256 + hb;
        addrs.z = (rowB + x0c) * 256 + hb;
        addrs.w = (rowB + x1c) * 256 + hb;
        int4 wts;
        wts.x = __float_as_int((1.f - wx1) * vx0);
        wts.y = __float_as_int(wx1 * vx1);
        wts.z = __float_as_int(aw * (1.f - wy1) * vy0);
        wts.w = __float_as_int(aw * wy1 * vy1);
        const int slot = (lane & 15) * 2 + (lane >> 4);
        SA[qi][slot] = addrs;
        SW[qi][slot] = wts;
    }
    __syncthreads();

    // ---- phase 2: gather + packed-f32 weighted accumulate ----
    const char* vb = (const char*)(value_bf + (size_t)b * NQ * 128);
    const int cb = (lane & 15) * 4;    // channel-pair byte offset within head
    const int g16 = lane >> 4;         // 0 -> heads 0,1 ; 1 -> heads 2,3

    f32x2 acc[2][2];                   // [head-in-group][even/odd ILP split]
    acc[0][0] = (f32x2){0.f, 0.f}; acc[0][1] = (f32x2){0.f, 0.f};
    acc[1][0] = (f32x2){0.f, 0.f}; acc[1][1] = (f32x2){0.f, 0.f};

#pragma unroll
    for (int i = 0; i < 16; ++i) {
        const int slot = 2 * i + g16;
        int4 ai = SA[qi][slot];
        int4 wi = SW[qi][slot];
        f32x2 wxa2 = (f32x2){__int_as_float(wi.x), __int_as_float(wi.x)};
        f32x2 wxb2 = (f32x2){__int_as_float(wi.y), __int_as_float(wi.y)};
        f32x2 wya2 = (f32x2){__int_as_float(wi.z), __int_as_float(wi.z)};
        f32x2 wyb2 = (f32x2){__int_as_float(wi.w), __int_as_float(wi.w)};

        unsigned int u00 = *(const unsigned int*)(vb + ai.x + cb);
        unsigned int u01 = *(const unsigned int*)(vb + ai.y + cb);
        unsigned int u10 = *(const unsigned int*)(vb + ai.z + cb);
        unsigned int u11 = *(const unsigned int*)(vb + ai.w + cb);

        f32x2 f00 = (f32x2){__uint_as_float(u00 << 16), __uint_as_float(u00 & 0xFFFF0000u)};
        f32x2 f01 = (f32x2){__uint_as_float(u01 << 16), __uint_as_float(u01 & 0xFFFF0000u)};
        f32x2 f10 = (f32x2){__uint_as_float(u10 << 16), __uint_as_float(u10 & 0xFFFF0000u)};
        f32x2 f11 = (f32x2){__uint_as_float(u11 << 16), __uint_as_float(u11 & 0xFFFF0000u)};

        f32x2 ta = __builtin_elementwise_fma(wxa2, f00, wxb2 * f01);
        f32x2 tb = __builtin_elementwise_fma(wxa2, f10, wxb2 * f11);

        const int j = i >> 3, k = i & 1;   // compile-time after unroll
        acc[j][k] = __builtin_elementwise_fma(wya2, ta, acc[j][k]);
        acc[j][k] = __builtin_elementwise_fma(wyb2, tb, acc[j][k]);
    }

    // write: head h = g16*2 + j, channel pair (lane&15)*2, packed u32
    char* sp = (char*)(sampled + (size_t)r * 128);
#pragma unroll
    for (int j = 0; j < 2; ++j) {
        f32x2 a2 = acc[j][0] + acc[j][1];
        unsigned int packed = ((unsigned int)f2bf(a2[1]) << 16) | (unsigned int)f2bf(a2[0]);
        *(unsigned int*)(sp + (g16 * 2 + j) * 64 + cb) = packed;
    }
}

// ---- G2: out = sampled @ W12 + b12 + query. B in registers, 2 groups of 4 tiles
// (siblings same XCD), swapped MFMA -> float4 stores with fused residual read. ----
__global__ __launch_bounds__(256, 2) void g2_kernel(
    const unsigned short* __restrict__ sampled, const unsigned short* __restrict__ W12T,
    const float* __restrict__ b12, const float* __restrict__ query, float* __restrict__ out)
{
    const int tid = threadIdx.x;
    const int group = blockIdx.x >> 9;         // 0..1, siblings same XCD
    const int gblk = blockIdx.x & 511;
    const int lane = tid & 63;
    const int arow = lane & 15, kq = lane >> 4;
    const int wid = gblk * 4 + (tid >> 6);     // 0..2047 within group
    const int tg0 = group * 4;

    short8 bf[4][4];
#pragma unroll
    for (int t = 0; t < 4; ++t)
#pragma unroll
        for (int ks = 0; ks < 4; ++ks)
            bf[t][ks] = *(const short8*)(W12T + (size_t)((tg0 + t) * 16 + arow) * 128 + ks * 32 + kq * 8);

    f32x4 biasv[4];
#pragma unroll
    for (int t = 0; t < 4; ++t) {
        float4 b4 = *(const float4*)(b12 + (tg0 + t) * 16 + kq * 4);
        biasv[t] = (f32x4){b4.x, b4.y, b4.z, b4.w};
    }

    for (int tile = wid; tile < NTILES; tile += 2048) {
        const char* pa = (const char*)sampled + (size_t)(tile * 16 + arow) * 256 + kq * 16;
        short8 af[4];
#pragma unroll
        for (int ks = 0; ks < 4; ++ks) af[ks] = *(const short8*)(pa + ks * 64);

        f32x4 acc[4];
#pragma unroll
        for (int t = 0; t < 4; ++t) acc[t] = biasv[t];

#pragma unroll
        for (int ks = 0; ks < 4; ++ks)
#pragma unroll
            for (int t = 0; t < 4; ++t)
                acc[t] = __builtin_amdgcn_mfma_f32_16x16x32_bf16(bf[t][ks], af[ks], acc[t], 0, 0, 0);

        const int row = tile * 16 + arow;
#pragma unroll
        for (int t = 0; t < 4; ++t) {
            size_t idx = (size_t)row * 128 + (tg0 + t) * 16 + kq * 4;
            float4 q4 = *(const float4*)(query + idx);
            float4 o = make_float4(acc[t][0] + q4.x, acc[t][1] + q4.y,
                                   acc[t][2] + q4.z, acc[t][3] + q4.w);
            *(float4*)(out + idx) = o;
        }
    }
}

extern "C" void kernel_launch(void* const* d_in, const int* in_sizes, int n_in,
                              void* d_out, int out_size, void* d_ws, size_t ws_size,
                              hipStream_t stream) {
    const float* query = (const float*)d_in[0];
    const float* qpos  = (const float*)d_in[1];
    const float* Wv    = (const float*)d_in[2];
    const float* bv    = (const float*)d_in[3];
    const float* Woff  = (const float*)d_in[4];
    const float* boff  = (const float*)d_in[5];
    const float* Wattn = (const float*)d_in[6];
    const float* battn = (const float*)d_in[7];
    const float* Wout1 = (const float*)d_in[8];
    const float* bout1 = (const float*)d_in[9];
    const float* Wout2 = (const float*)d_in[10];
    const float* bout2 = (const float*)d_in[11];
    float* out = (float*)d_out;

    char* ws = (char*)d_ws;
    unsigned short* value_bf = (unsigned short*)(ws);                 // 80000*128*2 = 20,480,000
    float*          off_buf  = (float*)(ws + 20480000);               // 80000*64*4  = 20,480,000
    float*          logits   = (float*)(ws + 40960000);               // 80000*32*4  = 10,240,000
    unsigned short* sampled  = (unsigned short*)(ws + 51200000);      // 80000*128*2 = 20,480,000
    unsigned short* WcatT    = (unsigned short*)(ws + 71680000);      // 224*128*2   = 57,344
    unsigned short* W12T     = (unsigned short*)(ws + 71680000 + 57344);  // 128*128*2 = 32,768
    float*          b12      = (float*)(ws + 71680000 + 57344 + 32768);   // 512

    // qbf aliases `sampled`: qbf is dead before sample_kernel writes sampled.
    unsigned short* qbf = sampled;

    prep_wcat<<<112, 256, 0, stream>>>(Wv, Woff, Wattn, WcatT);
    prep_w12<<<64, 256, 0, stream>>>(Wout1, Wout2, bout1, bout2, W12T, b12);
    qsum_kernel<<<2048, 256, 0, stream>>>(query, qpos, qbf);
    g1_kernel<<<1024, 256, 0, stream>>>(qbf, WcatT, bv, boff, battn,
                                        value_bf, off_buf, logits);
    sample_kernel<<<MTOT / 8, 256, 0, stream>>>(value_bf, off_buf, logits, sampled);
    g2_kernel<<<1024, 256, 0, stream>>>(sampled, W12T, b12, query, out);
}